// Round 1
// baseline (82.523 us; speedup 1.0000x reference)
//
#include <hip/hip_runtime.h>

#define LENGTH 4000
#define NPAD   4096
#define NB     8
#define CH     64
#define NP     4
#define OSPLIT 4
#define OPB    (CH / OSPLIT)   // 16 outputs per block
#define NCHCOL 256             // n-columns per mix block
#define NCHUNKS (NPAD / NCHCOL) // 16

// ---------------- K1: forward FWHT of zero-padded x rows -> f1 ----------------
__global__ __launch_bounds__(256) void k_fwht_fwd(const float* __restrict__ x,
                                                  float* __restrict__ f1) {
    __shared__ float s[NPAD];
    const int row = blockIdx.x;            // b*64 + i
    const int t = threadIdx.x;
    const float* xr = x + (size_t)row * LENGTH;
    #pragma unroll
    for (int j = 0; j < NPAD / 256; ++j) {
        int n = j * 256 + t;
        s[n] = (n < LENGTH) ? xr[n] : 0.f;
    }
    for (int h = 1; h < NPAD; h <<= 1) {
        __syncthreads();
        #pragma unroll
        for (int j = 0; j < NPAD / 512; ++j) {
            int k = j * 256 + t;
            int idx = ((k & ~(h - 1)) << 1) | (k & (h - 1));
            float a = s[idx], c = s[idx + h];
            s[idx] = a + c;
            s[idx + h] = a - c;
        }
    }
    __syncthreads();
    float* fr = f1 + (size_t)row * NPAD;
    #pragma unroll
    for (int j = 0; j < NPAD / 256; ++j) {
        int n = j * 256 + t;
        fr[n] = s[n];
    }
}

// ---------------- K2: per-column channel mix + soft-threshold + sum over p ----
__global__ __launch_bounds__(256) void k_mix(const float* __restrict__ f1,
                                             const float* __restrict__ W,
                                             const float* __restrict__ T,
                                             const float* __restrict__ v,
                                             float* __restrict__ f6) {
    const int bid = blockIdx.x;            // b*(NCHUNKS*OSPLIT) + chunk*OSPLIT + oq
    const int oq = bid & (OSPLIT - 1);
    const int chunk = (bid / OSPLIT) & (NCHUNKS - 1);
    const int b = bid / (OSPLIT * NCHUNKS);
    const int n = chunk * NCHCOL + threadIdx.x;

    float col[CH];
    #pragma unroll
    for (int i = 0; i < CH; ++i)
        col[i] = f1[(size_t)(b * CH + i) * NPAD + n];

    float vp[NP], tp[NP];
    #pragma unroll
    for (int p = 0; p < NP; ++p) {
        vp[p] = v[p * NPAD + n];
        tp[p] = fabsf(T[p * NPAD + n]);
    }

    for (int o = 0; o < OPB; ++o) {
        const int oo = oq * OPB + o;
        float acc = 0.f;
        #pragma unroll
        for (int p = 0; p < NP; ++p) {
            const float* wr = W + (size_t)(p * CH + oo) * CH;
            float g0 = 0.f, g1 = 0.f;
            #pragma unroll
            for (int i = 0; i < CH; i += 2) {
                g0 = fmaf(wr[i],     col[i],     g0);
                g1 = fmaf(wr[i + 1], col[i + 1], g1);
            }
            float c = vp[p] * (g0 + g1);
            float a = fabsf(c) - tp[p];
            acc += (a > 0.f) ? copysignf(a, c) : 0.f;
        }
        f6[(size_t)(b * CH + oo) * NPAD + n] = acc;
    }
}

// ---------------- K3: inverse FWHT (scaled), truncate, add x -> out -----------
__global__ __launch_bounds__(256) void k_fwht_inv(const float* __restrict__ f6,
                                                  const float* __restrict__ x,
                                                  float* __restrict__ out) {
    __shared__ float s[NPAD];
    const int row = blockIdx.x;            // b*64 + o
    const int t = threadIdx.x;
    const float* fr = f6 + (size_t)row * NPAD;
    #pragma unroll
    for (int j = 0; j < NPAD / 256; ++j) {
        int n = j * 256 + t;
        s[n] = fr[n];
    }
    for (int h = 1; h < NPAD; h <<= 1) {
        __syncthreads();
        #pragma unroll
        for (int j = 0; j < NPAD / 512; ++j) {
            int k = j * 256 + t;
            int idx = ((k & ~(h - 1)) << 1) | (k & (h - 1));
            float a = s[idx], c = s[idx + h];
            s[idx] = a + c;
            s[idx + h] = a - c;
        }
    }
    __syncthreads();
    const float* xr = x + (size_t)row * LENGTH;
    float* orow = out + (size_t)row * LENGTH;
    const float scale = 1.f / NPAD;
    #pragma unroll
    for (int j = 0; j < NPAD / 256; ++j) {
        int n = j * 256 + t;
        if (n < LENGTH) orow[n] = s[n] * scale + xr[n];
    }
}

extern "C" void kernel_launch(void* const* d_in, const int* in_sizes, int n_in,
                              void* d_out, int out_size, void* d_ws, size_t ws_size,
                              hipStream_t stream) {
    (void)in_sizes; (void)n_in; (void)out_size; (void)ws_size;
    const float* x = (const float*)d_in[0];
    const float* W = (const float*)d_in[1];
    const float* T = (const float*)d_in[2];
    const float* v = (const float*)d_in[3];
    float* out = (float*)d_out;
    float* f1 = (float*)d_ws;
    float* f6 = f1 + (size_t)NB * CH * NPAD;

    k_fwht_fwd<<<NB * CH, 256, 0, stream>>>(x, f1);
    k_mix<<<NB * NCHUNKS * OSPLIT, 256, 0, stream>>>(f1, W, T, v, f6);
    k_fwht_inv<<<NB * CH, 256, 0, stream>>>(f6, x, out);
}